// Round 16
// baseline (49.072 us; speedup 1.0000x reference)
//
#include <hip/hip_runtime.h>
#include <math.h>

#define KW 11
#define HALO 10
#define TY 32
#define BATCH 32
#define HH 512
#define WW 512
#define OH 502
#define OW 502
#define SPW 128        // strip width: output cols per wave (2 per lane)
#define NSX 4          // 4 strips x 128 = 512
#define WPB 2          // independent waves per block (no __syncthreads)
#define NBX 2
#define NBY 16
#define NWAVE (BATCH * NBY * NSX)   // 2048
#define C3V 1.0e-4f
#define SW 144         // slot stride in v2f: 138 data + 6 pad (16B-aligned)

typedef float v2f __attribute__((ext_vector_type(2)));

static __device__ __forceinline__ float rfl(float x) {
    return __int_as_float(__builtin_amdgcn_readfirstlane(__float_as_int(x)));
}

// R10's proven skeleton (2 cols/lane, RDWIN(p) at phase start, yr<rows guard,
// branch-masked epilogue) + R13's proven distance-2 global->LDS staging:
//   phase p (row yr): 1) ds_read slot p -> W (written last phase)
//                     2) ds_write row yr+1 -> slot p+1 (load is 2 phases old)
//                     3) global load row yr+3 into the freed staging set
//                     4) shared-square dual h-conv from W
//                     5) dual v-conv (register-rotated) + fused epilogue
// Staging set = phase parity (compile-time after unroll); sets swap at chunk
// end (11 phases flip parity).
__global__ __launch_bounds__(128) void ssim_strip_kernel(
    const float* __restrict__ in1,
    const float* __restrict__ in2,
    const float* __restrict__ win,
    double* __restrict__ partials)
{
    __shared__ v2f sh[WPB][KW][SW];   // 25344 B

    const int t = threadIdx.x;
    const int wid = t >> 6;
    const int lane = t & 63;
    const int strip = blockIdx.x * WPB + wid;
    const int x0 = strip * SPW;
    const int y0 = blockIdx.y * TY;
    const int img = blockIdx.z;

    const int ny = min(TY, OH - y0);     // 32, last y-strip 22
    const int rows = ny + HALO;          // 42 or 32

    // separable 1D gaussian; symmetric: g[j] == g[10-j] -> 6 unique splats
    v2f gp[6];
    {
        const float c = sqrtf(win[5 * KW + 5]);
        #pragma unroll
        for (int i = 0; i < 6; ++i) {
            const float w = rfl(win[i * KW + 5] / c);
            gp[i] = (v2f){w, w};
        }
    }
    #define GW(j) gp[(j) <= 5 ? (j) : 10 - (j)]

    // two output cols per lane; column validity masks
    const int cA = x0 + 2 * lane;              // <= 510: in-bounds reads
    const v2f mcol = (v2f){ cA < OW ? 1.f : 0.f, (cA + 1) < OW ? 1.f : 0.f };

    const float* b1 = in1 + (size_t)img * HH * WW;
    const float* b2 = in2 + (size_t)img * HH * WW;
    const int hc = min(x0 + SPW + 2 * lane, WW - 2);   // halo cols, lanes 0..4
    const bool hstage = lane < 5;

    v2f* const mysh = &sh[wid][0][0];          // slot stride = SW v2f

    // dual staging sets (A/B): written 2 phases after their load
    v2f vaA = (v2f){0.f, 0.f}, vbA = (v2f){0.f, 0.f};
    v2f haA = (v2f){0.f, 0.f}, hbA = (v2f){0.f, 0.f};
    v2f vaB = (v2f){0.f, 0.f}, vbB = (v2f){0.f, 0.f};
    v2f haB = (v2f){0.f, 0.f}, hbB = (v2f){0.f, 0.f};

#define LOADR_A(q) { const int rq = min(y0 + (q), HH - 1);                 \
    const float* r1 = b1 + (size_t)rq * WW;                                \
    const float* r2 = b2 + (size_t)rq * WW;                                \
    vaA = *(const v2f*)(r1 + cA); vbA = *(const v2f*)(r2 + cA);            \
    if (hstage) { haA = *(const v2f*)(r1 + hc); hbA = *(const v2f*)(r2 + hc); } }
#define LOADR_B(q) { const int rq = min(y0 + (q), HH - 1);                 \
    const float* r1 = b1 + (size_t)rq * WW;                                \
    const float* r2 = b2 + (size_t)rq * WW;                                \
    vaB = *(const v2f*)(r1 + cA); vbB = *(const v2f*)(r2 + cA);            \
    if (hstage) { haB = *(const v2f*)(r1 + hc); hbB = *(const v2f*)(r2 + hc); } }
#define WRITES_A(slot) {                                                    \
    *(float4*)&mysh[(slot) * SW + 2 * lane] =                               \
        make_float4(vaA.x, vbA.x, vaA.y, vbA.y);                            \
    if (hstage) *(float4*)&mysh[(slot) * SW + SPW + 2 * lane] =             \
        make_float4(haA.x, hbA.x, haA.y, hbA.y); }
#define WRITES_B(slot) {                                                    \
    *(float4*)&mysh[(slot) * SW + 2 * lane] =                               \
        make_float4(vaB.x, vbB.x, vaB.y, vbB.y);                            \
    if (hstage) *(float4*)&mysh[(slot) * SW + SPW + 2 * lane] =             \
        make_float4(haB.x, hbB.x, haB.y, hbB.y); }

    v2f W[12];
#define RDWIN(slot) { const v2f* rp = mysh + (slot) * SW + 2 * lane;        \
    _Pragma("unroll") for (int j = 0; j < 6; ++j)                           \
        *(float4*)&W[2 * j] = *(const float4*)&rp[2 * j]; }

    // vertical accumulators, per column: (a,b) pk, (aa,bb) pk, ab scalar
    v2f aabA[KW], asqA[KW], aabB[KW], asqB[KW];
    float a4A[KW], a4B[KW];
    #pragma unroll
    for (int i = 0; i < KW; ++i) {
        aabA[i] = (v2f){0.f, 0.f}; asqA[i] = (v2f){0.f, 0.f}; a4A[i] = 0.f;
        aabB[i] = (v2f){0.f, 0.f}; asqB[i] = (v2f){0.f, 0.f}; a4B[i] = 0.f;
    }

    double tsum = 0.0;

    // prologue: slot0 = row 0; A = row 1 (next write), B = row 2
    LOADR_A(0); WRITES_A(0);
    LOADR_A(1);
    LOADR_B(2);

    for (int c = 0; c < 4; ++c) {        // 44 phases; guarded past `rows`
        v2f csum = (v2f){0.f, 0.f};
        #pragma unroll
        for (int p = 0; p < KW; ++p) {
            const int yr = c * KW + p;
            if (yr < rows) {             // wave-uniform guard (region boundary)
                RDWIN(p);                            // row yr window (12 v2f)
                // stage row yr+1 (loaded 2 phases ago) into slot p+1;
                // reload the freed set with row yr+3
                if ((p & 1) == 0) { WRITES_A((p + 1) % KW); LOADR_A(yr + 3); }
                else              { WRITES_B((p + 1) % KW); LOADR_B(yr + 3); }

                // shared squares + dual h-conv (colA taps 0-10, colB taps 1-11)
                v2f habA = (v2f){0.f, 0.f}, hsqA = (v2f){0.f, 0.f};
                v2f habB = (v2f){0.f, 0.f}, hsqB = (v2f){0.f, 0.f};
                float h4A = 0.f, h4B = 0.f;
                #pragma unroll
                for (int j = 0; j < 12; ++j) {
                    const v2f ab = W[j];
                    const v2f sq = ab * ab;            // pk_mul, shared
                    const float p4 = ab.x * ab.y;      // mul, shared
                    if (j < 11) {
                        const v2f g = GW(j);
                        habA = __builtin_elementwise_fma(g, ab, habA);
                        hsqA = __builtin_elementwise_fma(g, sq, hsqA);
                        h4A = fmaf(g.x, p4, h4A);
                    }
                    if (j > 0) {
                        const v2f g = GW(j - 1);
                        habB = __builtin_elementwise_fma(g, ab, habB);
                        hsqB = __builtin_elementwise_fma(g, sq, hsqB);
                        h4B = fmaf(g.x, p4, h4B);
                    }
                }

                // dual vertical accumulate: slot j -> register (j+p)%11;
                // slot 10 is the first tap -> overwrite (no reset)
                #pragma unroll
                for (int r = 0; r < KW; ++r) {
                    const int j = (r - p + KW) % KW;
                    const v2f g = GW(10 - j);
                    if (j == 10) {
                        aabA[r] = g * habA; asqA[r] = g * hsqA; a4A[r] = g.x * h4A;
                        aabB[r] = g * habB; asqB[r] = g * hsqB; a4B[r] = g.x * h4B;
                    } else {
                        aabA[r] = __builtin_elementwise_fma(g, habA, aabA[r]);
                        asqA[r] = __builtin_elementwise_fma(g, hsqA, asqA[r]);
                        a4A[r] = fmaf(g.x, h4A, a4A[r]);
                        aabB[r] = __builtin_elementwise_fma(g, habB, aabB[r]);
                        asqB[r] = __builtin_elementwise_fma(g, hsqB, asqB[r]);
                        a4B[r] = fmaf(g.x, h4B, a4B[r]);
                    }
                }

                // register p completes -> output row yr-10 (wave-uniform)
                if (yr >= HALO && (yr - HALO) < ny) {
                    const v2f muA = aabA[p], muB = aabB[p];
                    const v2f sqA = __builtin_elementwise_fma(-muA, muA, asqA[p]);
                    const v2f sqB = __builtin_elementwise_fma(-muB, muB, asqB[p]);
                    const float s12A = fmaf(-muA.x, muA.y, a4A[p]);
                    const float s12B = fmaf(-muB.x, muB.y, a4B[p]);
                    const float dA = __builtin_amdgcn_sqrtf(fabsf(sqA.x * sqA.y)) + C3V;
                    const float dB = __builtin_amdgcn_sqrtf(fabsf(sqB.x * sqB.y)) + C3V;
                    const v2f s2 = (v2f){ (s12A + C3V) * __builtin_amdgcn_rcpf(dA),
                                          (s12B + C3V) * __builtin_amdgcn_rcpf(dB) };
                    csum = __builtin_elementwise_fma(s2, mcol, csum);
                }
            }
        }
        tsum += (double)csum.x + (double)csum.y;
        // 11 phases flip staging parity: swap sets
        { v2f tmp;
          tmp = vaA; vaA = vaB; vaB = tmp;
          tmp = vbA; vbA = vbB; vbB = tmp;
          tmp = haA; haA = haB; haB = tmp;
          tmp = hbA; hbA = hbB; hbB = tmp; }
    }
#undef LOADR_A
#undef LOADR_B
#undef WRITES_A
#undef WRITES_B
#undef RDWIN
#undef GW

    // per-wave deterministic reduction
    #pragma unroll
    for (int off = 32; off > 0; off >>= 1)
        tsum += __shfl_down(tsum, off, 64);
    if (lane == 0) {
        const int bid = (img * NBY + blockIdx.y) * NSX + strip;
        partials[bid] = tsum;
    }
}

// deterministic final reduce of the 2048 wave partials -> mean
__global__ __launch_bounds__(256) void ssim_reduce_kernel(
    const double* __restrict__ partials, float* __restrict__ out)
{
    __shared__ double sred[4];
    double s = 0.0;
    for (int i = threadIdx.x; i < NWAVE; i += 256) s += partials[i];
    #pragma unroll
    for (int off = 32; off > 0; off >>= 1)
        s += __shfl_down(s, off, 64);
    const int wid = threadIdx.x >> 6;
    const int lane = threadIdx.x & 63;
    if (lane == 0) sred[wid] = s;
    __syncthreads();
    if (threadIdx.x == 0) {
        const double total = sred[0] + sred[1] + sred[2] + sred[3];
        out[0] = (float)(total / ((double)BATCH * OH * OW));
    }
}

extern "C" void kernel_launch(void* const* d_in, const int* in_sizes, int n_in,
                              void* d_out, int out_size, void* d_ws, size_t ws_size,
                              hipStream_t stream) {
    const float* in1 = (const float*)d_in[0];
    const float* in2 = (const float*)d_in[1];
    const float* win = (const float*)d_in[2];
    float* out = (float*)d_out;
    double* partials = (double*)d_ws;   // 2048 doubles = 16 KB

    dim3 grid(NBX, NBY, BATCH);
    dim3 block(WPB * 64);
    ssim_strip_kernel<<<grid, block, 0, stream>>>(in1, in2, win, partials);
    ssim_reduce_kernel<<<1, 256, 0, stream>>>(partials, out);
}

// Round 17
// 46.870 us; speedup vs baseline: 1.0470x; 1.0470x over previous
//
#include <hip/hip_runtime.h>
#include <math.h>

#define KW 11
#define HALO 10
#define TY 32
#define BATCH 32
#define HH 512
#define WW 512
#define OH 502
#define OW 502
#define NSX 8          // 8 strips x 64 cols
#define WPB 4          // independent waves per block (no __syncthreads)
#define NBX 2
#define NBY 16
#define NWAVE (BATCH * NBY * NSX)   // 4096
#define C3V 1.0e-4f
#define SW 80          // staged cols per row (64 + 16 halo), one v2f (a,b) each

typedef float v2f __attribute__((ext_vector_type(2)));

static __device__ __forceinline__ float rfl(float x) {
    return __int_as_float(__builtin_amdgcn_readfirstlane(__float_as_int(x)));
}

// 4 independent waves/block (no __syncthreads); each wave owns a 64-col strip,
// 44 rows through an 11-slot wave-private LDS ring of interleaved (a,b) rows.
// R13's proven phase body + distance-2 global->LDS staging via dual register
// sets; s_setprio(1) wraps the compute section (waves are barrier-free and
// phase-skewed -> priority arbitration has role diversity to exploit):
//   phase p (row yr): 1) h-conv from W (row yr)            [setprio 1]
//                     2) ds_write row yr+1 -> slot p+1 (load is 2 phases old)
//                     3) ds_read slot p+1 -> W
//                     4) global load row yr+3 into the freed set
//                     5) v-conv (register-rotated) + epilogue [setprio 1]
__global__ __launch_bounds__(256) void ssim_strip_kernel(
    const float* __restrict__ in1,
    const float* __restrict__ in2,
    const float* __restrict__ win,
    double* __restrict__ partials)
{
    __shared__ v2f sh[WPB][KW][SW];   // 28160 B

    const int t = threadIdx.x;
    const int wid = t >> 6;
    const int lane = t & 63;
    const int strip = blockIdx.x * WPB + wid;
    const int x0 = strip * 64;
    const int y0 = blockIdx.y * TY;
    const int img = blockIdx.z;

    const int nx = min(64, OW - x0);     // 64, last strip 54
    const int ny = min(TY, OH - y0);     // 32, last y-strip 22

    // separable 1D gaussian; symmetric: g[j] == g[10-j] -> 6 unique splats
    v2f gp[6];
    {
        const float c = sqrtf(win[5 * KW + 5]);
        #pragma unroll
        for (int i = 0; i < 6; ++i) {
            const float w = rfl(win[i * KW + 5] / c);
            gp[i] = (v2f){w, w};
        }
    }
    #define GW(j) gp[(j) <= 5 ? (j) : 10 - (j)]

    const float maskf = (lane < nx) ? 1.f : 0.f;
    const bool stager = lane < 40;                    // 40 lanes x 2 cols = 80
    const int scol = min(x0 + 2 * lane, WW - 2);      // clamped: no OOB
    const float* b1 = in1 + (size_t)img * HH * WW;
    const float* b2 = in2 + (size_t)img * HH * WW;

    v2f* const mysh = &sh[wid][0][0];                 // slot stride = SW v2f

    // dual staging sets: at phase p (even->A, odd->B) the set holds row yr+1
    v2f vaA, vbA, vaB, vbB;

#define LOADR_A(q) { const int rq = min(y0 + (q), HH - 1);            \
    vaA = *(const v2f*)(b1 + (size_t)rq * WW + scol);                 \
    vbA = *(const v2f*)(b2 + (size_t)rq * WW + scol); }
#define LOADR_B(q) { const int rq = min(y0 + (q), HH - 1);            \
    vaB = *(const v2f*)(b1 + (size_t)rq * WW + scol);                 \
    vbB = *(const v2f*)(b2 + (size_t)rq * WW + scol); }
#define WRITES_A(slot) { if (stager)                                   \
    *(float4*)&mysh[(slot) * SW + 2 * lane] =                          \
        make_float4(vaA.x, vbA.x, vaA.y, vbA.y); }
#define WRITES_B(slot) { if (stager)                                   \
    *(float4*)&mysh[(slot) * SW + 2 * lane] =                          \
        make_float4(vaB.x, vbB.x, vaB.y, vbB.y); }
#define RDWIN(slot) { const v2f* rp = mysh + (slot) * SW + lane;       \
    _Pragma("unroll") for (int j = 0; j < KW; ++j) W[j] = rp[j]; }

    // vertical accumulators: (a,b) packed, (aa,bb) packed, ab scalar
    v2f accab[KW], accsq[KW];
    float acc4[KW];
    #pragma unroll
    for (int i = 0; i < KW; ++i) {
        accab[i] = (v2f){0.f, 0.f}; accsq[i] = (v2f){0.f, 0.f}; acc4[i] = 0.f;
    }

    v2f W[KW];
    double tsum = 0.0;

    // prologue: row 0 staged + window loaded; row 1 -> set A, row 2 -> set B
    LOADR_A(0);
    WRITES_A(0);
    RDWIN(0);
    LOADR_A(1);
    LOADR_B(2);

#define PHASE(p, S) {                                                   \
    const int yr = cbase + (p);                                         \
    /* 1) horizontal 11-tap conv from W (row yr), packed channels */    \
    __builtin_amdgcn_s_setprio(1);                                      \
    v2f hab = (v2f){0.f, 0.f}, hsq = (v2f){0.f, 0.f};                   \
    float h4 = 0.f;                                                     \
    _Pragma("unroll")                                                   \
    for (int j = 0; j < KW; ++j) {                                      \
        const v2f ab = W[j];                                            \
        const v2f g = GW(j);                                            \
        const v2f gab = g * ab;                                         \
        hab = __builtin_elementwise_fma(g, ab, hab);                    \
        hsq = __builtin_elementwise_fma(gab, ab, hsq);                  \
        h4 = fmaf(gab.x, ab.y, h4);                                     \
    }                                                                   \
    __builtin_amdgcn_s_setprio(0);                                      \
    /* 2) stage row yr+1 (loaded 2 phases ago) into slot p+1 */         \
    WRITES_##S(((p) + 1) % KW);                                         \
    /* 3) refill W with row yr+1's window */                            \
    RDWIN(((p) + 1) % KW);                                              \
    /* 4) reload freed set with row yr+3 */                             \
    LOADR_##S(yr + 3);                                                  \
    /* 5) vertical accumulate: slot j -> register (j+p)%11; slot 10 */  \
    /*    is the first tap -> overwrite (no reset) */                   \
    __builtin_amdgcn_s_setprio(1);                                      \
    _Pragma("unroll")                                                   \
    for (int r = 0; r < KW; ++r) {                                      \
        const int j = (r - (p) + KW) % KW;                              \
        const v2f g = GW(10 - j);                                       \
        if (j == 10) {                                                  \
            accab[r] = g * hab;                                         \
            accsq[r] = g * hsq;                                         \
            acc4[r] = g.x * h4;                                         \
        } else {                                                        \
            accab[r] = __builtin_elementwise_fma(g, hab, accab[r]);     \
            accsq[r] = __builtin_elementwise_fma(g, hsq, accsq[r]);     \
            acc4[r] = fmaf(g.x, h4, acc4[r]);                           \
        }                                                               \
    }                                                                   \
    /* 6) register p completes -> output row yr-10 (uniform branch) */  \
    if (yr >= HALO) {                                                   \
        const v2f mu = accab[(p)];                                      \
        const v2f sq = __builtin_elementwise_fma(-mu, mu, accsq[(p)]);  \
        const float s12 = fmaf(-mu.x, mu.y, acc4[(p)]);                 \
        const float den = __builtin_amdgcn_sqrtf(fabsf(sq.x * sq.y)) + C3V; \
        const float s = (s12 + C3V) * __builtin_amdgcn_rcpf(den);       \
        const float m = ((yr - HALO) < ny) ? maskf : 0.f;               \
        csum = fmaf(s, m, csum);                                        \
    }                                                                   \
    __builtin_amdgcn_s_setprio(0);                                      \
}

    for (int c = 0; c < 4; ++c) {        // 44 rows total, fixed
        const int cbase = c * KW;
        float csum = 0.f;
        PHASE(0, A) PHASE(1, B) PHASE(2, A) PHASE(3, B) PHASE(4, A)
        PHASE(5, B) PHASE(6, A) PHASE(7, B) PHASE(8, A) PHASE(9, B)
        PHASE(10, A)
        tsum += (double)csum;
        // 11 phases flips parity: swap sets so "even phase -> A" stays true
        { v2f tmp;
          tmp = vaA; vaA = vaB; vaB = tmp;
          tmp = vbA; vbA = vbB; vbB = tmp; }
    }
#undef PHASE
#undef LOADR_A
#undef LOADR_B
#undef WRITES_A
#undef WRITES_B
#undef RDWIN
#undef GW

    // per-wave deterministic reduction
    #pragma unroll
    for (int off = 32; off > 0; off >>= 1)
        tsum += __shfl_down(tsum, off, 64);
    if (lane == 0) {
        const int bid = (img * NBY + blockIdx.y) * NSX + strip;
        partials[bid] = tsum;
    }
}

// deterministic final reduce of the 4096 wave partials -> mean
__global__ __launch_bounds__(256) void ssim_reduce_kernel(
    const double* __restrict__ partials, float* __restrict__ out)
{
    __shared__ double sred[4];
    double s = 0.0;
    for (int i = threadIdx.x; i < NWAVE; i += 256) s += partials[i];
    #pragma unroll
    for (int off = 32; off > 0; off >>= 1)
        s += __shfl_down(s, off, 64);
    const int wid = threadIdx.x >> 6;
    const int lane = threadIdx.x & 63;
    if (lane == 0) sred[wid] = s;
    __syncthreads();
    if (threadIdx.x == 0) {
        const double total = sred[0] + sred[1] + sred[2] + sred[3];
        out[0] = (float)(total / ((double)BATCH * OH * OW));
    }
}

extern "C" void kernel_launch(void* const* d_in, const int* in_sizes, int n_in,
                              void* d_out, int out_size, void* d_ws, size_t ws_size,
                              hipStream_t stream) {
    const float* in1 = (const float*)d_in[0];
    const float* in2 = (const float*)d_in[1];
    const float* win = (const float*)d_in[2];
    float* out = (float*)d_out;
    double* partials = (double*)d_ws;   // 4096 doubles = 32 KB

    dim3 grid(NBX, NBY, BATCH);
    dim3 block(WPB * 64);
    ssim_strip_kernel<<<grid, block, 0, stream>>>(in1, in2, win, partials);
    ssim_reduce_kernel<<<1, 256, 0, stream>>>(partials, out);
}